// Round 1
// baseline (427.363 us; speedup 1.0000x reference)
//
#include <hip/hip_runtime.h>
#include <hip/hip_fp16.h>

// Problem constants
#define BS    8192
#define DIM   256
#define KTOT  16384      // 128x128 codebook
#define CAND_CAP  131072     // survivor list (cand2)
#define CAND_CAP2 2097152    // raw emission list (aliases T, 16 MB)
#define LCAP 2048            // per-block LDS emission buffer entries
#define MARGIN 1.0f

typedef __attribute__((ext_vector_type(8))) _Float16 half8;
typedef __attribute__((ext_vector_type(4))) float f32x4;
typedef unsigned long long u64;

__device__ inline ushort f2h(float f) { return __half_as_ushort(__float2half(f)); }

// async global->LDS, 16B per lane; lds dest = wave-uniform base + lane*16
__device__ inline void gload_lds16(const void* g, void* l) {
    __builtin_amdgcn_global_load_lds(
        (const __attribute__((address_space(1))) unsigned int*)g,
        (__attribute__((address_space(3))) unsigned int*)l, 16, 0, 0);
}

// order-preserving f32 -> u32 map (ascending) and inverse
__device__ inline unsigned int fmap(float f) {
    unsigned int b = __float_as_uint(f);
    return (b & 0x80000000u) ? ~b : (b | 0x80000000u);
}
__device__ inline float unfmap(unsigned int m) {
    return (m & 0x80000000u) ? __uint_as_float(m & 0x7FFFFFFFu)
                             : __uint_as_float(~m);
}

// ---------------------------------------------------------------------------
// setup: zero S (16 MB), G table, zero cntf, init keys(u32)/keys2(u64), cnt[2].
__global__ void setup_all_kernel(float* __restrict__ S, float* __restrict__ G,
                                 float* __restrict__ cntf, unsigned int* __restrict__ keys,
                                 u64* __restrict__ keys2, unsigned int* __restrict__ cnt,
                                 const int* __restrict__ itp) {
    int idx = blockIdx.x * 256 + threadIdx.x;
    *(float4*)&S[(size_t)idx * 4] = make_float4(0.f, 0.f, 0.f, 0.f);
    if (idx < KTOT) {
        float itf = (float)itp[0];
        const float START_SIGMA = 64.0f;
        const float TAU = (float)(20.0 / 4.1588830833596715);  // 20 / ln(64)
        float sigma = START_SIGMA * expf(-itf / TAU);
        float d2 = 2.0f * sigma * sigma;
        int i = idx >> 7, j = idx & 127;
        float diff = (float)(i - j);
        G[idx] = expf(-(diff * diff) / d2);
        cntf[idx] = 0.f;
    }
    if (idx < BS) { keys[idx] = 0xFFFFFFFFu; keys2[idx] = ~0ULL; }
    if (idx == 0) { cnt[0] = 0u; cnt[1] = 0u; }
}

// ---------------------------------------------------------------------------
// x,w -> fp16 with XOR-swizzled 32-half windows (block c -> c ^ ((row>>1)&3)),
// + wsq for w rows.  One wave per row; rows [0,BS) are x, [BS, BS+KTOT) are w.
__global__ void cvt_all_kernel(const float* __restrict__ x, const float* __restrict__ w,
                               ushort* __restrict__ xf, ushort* __restrict__ wf,
                               float* __restrict__ wsq) {
    int wid = threadIdx.x >> 6, lane = threadIdx.x & 63;
    int row = blockIdx.x * 4 + wid;
    int h = lane * 4;                      // half index 0..255
    int window = h >> 5, c = (h >> 3) & 3, off = h & 7;
    if (row < BS) {
        int swpos = (window << 5) + (((c ^ ((row >> 1) & 3)) << 3)) + off;
        float4 v = *(const float4*)&x[(size_t)row * DIM + h];
        ushort4 hv;
        hv.x = f2h(v.x); hv.y = f2h(v.y); hv.z = f2h(v.z); hv.w = f2h(v.w);
        *(ushort4*)&xf[(size_t)row * DIM + swpos] = hv;
    } else {
        int r = row - BS;
        int swpos = (window << 5) + (((c ^ ((r >> 1) & 3)) << 3)) + off;
        float4 v = *(const float4*)&w[(size_t)r * DIM + h];
        ushort4 hv;
        hv.x = f2h(v.x); hv.y = f2h(v.y); hv.z = f2h(v.z); hv.w = f2h(v.w);
        *(ushort4*)&wf[(size_t)r * DIM + swpos] = hv;
        float s = v.x * v.x + v.y * v.y + v.z * v.z + v.w * v.w;
        #pragma unroll
        for (int o = 32; o; o >>= 1) s += __shfl_down(s, o, 64);
        if (lane == 0) wsq[r] = s;
    }
}

// ---------------------------------------------------------------------------
// Fused BMU pass: single fp16 GEMM.  Per 128-k tile: wave-reduce a per-sample
// running min (wbest); emit every score <= wbest + MARGIN into a per-block
// LDS buffer (superset of the global-margin candidate set, since the running
// min is always >= the final global min).  Flush once per block.  keys[s] =
// atomicMin of fmap(final wave/block min).
__global__ __launch_bounds__(256, 4) void bmu_fused_kernel(
    const ushort* __restrict__ xf, const ushort* __restrict__ wf,
    const float* __restrict__ wsq, unsigned int* __restrict__ keys,
    u64* __restrict__ cand, unsigned int* __restrict__ cnt) {
    __shared__ ushort A[128 * 32];   //  8 KB
    __shared__ ushort B[128 * 32];   //  8 KB
    __shared__ float red[128][2];
    __shared__ u64 lbuf[LCAP];       // 16 KB candidate staging
    __shared__ unsigned int lcnt, gbase_s;

    int m0 = blockIdx.x * 128;
    int kbase = blockIdx.y * 1024;
    int tid = threadIdx.x, w = tid >> 6, lane = tid & 63;
    int wm = (w & 1) * 64, wn = (w >> 1) * 64;
    int lm = lane & 15, quad = lane >> 4;
    int sw = (quad ^ ((lm >> 1) & 3)) * 8;   // conflict-free swizzled frag col
    int srow = lane >> 2, scol = (lane & 3) * 8;

    if (tid == 0) lcnt = 0u;

    // wave-level running min per sample row (replicated across the 16 lm lanes)
    float wbest[4][4];
    #pragma unroll
    for (int mi = 0; mi < 4; ++mi)
        #pragma unroll
        for (int r = 0; r < 4; ++r) wbest[mi][r] = 3.4e38f;

    for (int kt = 0; kt < 8; ++kt) {
        int k0 = kbase + kt * 128;
        f32x4 acc[4][4];
        #pragma unroll
        for (int mi = 0; mi < 4; ++mi)
            #pragma unroll
            for (int ni = 0; ni < 4; ++ni)
                acc[mi][ni] = (f32x4){0.f, 0.f, 0.f, 0.f};

        for (int kb = 0; kb < DIM; kb += 32) {
            size_t axoff = (size_t)(m0 + w * 32 + srow) * DIM + kb + scol;
            size_t bxoff = (size_t)(k0 + w * 32 + srow) * DIM + kb + scol;
            gload_lds16(xf + axoff,            &A[(w * 32) * 32]);
            gload_lds16(xf + axoff + 16 * DIM, &A[(w * 32 + 16) * 32]);
            gload_lds16(wf + bxoff,            &B[(w * 32) * 32]);
            gload_lds16(wf + bxoff + 16 * DIM, &B[(w * 32 + 16) * 32]);
            __syncthreads();
            half8 av[4], bv[4];
            #pragma unroll
            for (int mi = 0; mi < 4; ++mi)
                av[mi] = *(const half8*)&A[(wm + mi * 16 + lm) * 32 + sw];
            #pragma unroll
            for (int ni = 0; ni < 4; ++ni)
                bv[ni] = *(const half8*)&B[(wn + ni * 16 + lm) * 32 + sw];
            #pragma unroll
            for (int mi = 0; mi < 4; ++mi)
                #pragma unroll
                for (int ni = 0; ni < 4; ++ni)
                    acc[mi][ni] = __builtin_amdgcn_mfma_f32_16x16x32_f16(
                        av[mi], bv[ni], acc[mi][ni], 0, 0, 0);
            __syncthreads();
        }
        // fold + emit for this k-tile
        float wsqv[4];
        #pragma unroll
        for (int ni = 0; ni < 4; ++ni) wsqv[ni] = wsq[k0 + wn + ni * 16 + lm];
        #pragma unroll
        for (int mi = 0; mi < 4; ++mi)
            #pragma unroll
            for (int r = 0; r < 4; ++r) {
                float scv[4];
                #pragma unroll
                for (int ni = 0; ni < 4; ++ni)
                    scv[ni] = fmaf(-2.0f, acc[mi][ni][r], wsqv[ni]);
                float t = fminf(fminf(scv[0], scv[1]), fminf(scv[2], scv[3]));
                #pragma unroll
                for (int mask = 1; mask < 16; mask <<= 1)
                    t = fminf(t, __shfl_xor(t, mask, 64));
                float wb = fminf(wbest[mi][r], t);
                wbest[mi][r] = wb;
                float thr = wb + MARGIN;
                unsigned int sp =
                    (unsigned int)(m0 + wm + mi * 16 + quad * 4 + r) << 14;
                #pragma unroll
                for (int ni = 0; ni < 4; ++ni) {
                    if (scv[ni] <= thr) {
                        u64 v = ((u64)fmap(scv[ni]) << 32) |
                                (u64)(sp | (unsigned int)(k0 + wn + ni * 16 + lm));
                        unsigned int idx = atomicAdd(&lcnt, 1u);
                        if (idx < LCAP) lbuf[idx] = v;
                        else {                      // rare overflow fallback
                            unsigned int gi = atomicAdd(cnt, 1u);
                            if (gi < CAND_CAP2) cand[gi] = v;
                        }
                    }
                }
            }
    }
    // epilogue: per-sample min -> keys (wbest already lane-reduced)
    #pragma unroll
    for (int mi = 0; mi < 4; ++mi)
        #pragma unroll
        for (int r = 0; r < 4; ++r)
            if (lm == 0) red[wm + mi * 16 + quad * 4 + r][w >> 1] = wbest[mi][r];
    __syncthreads();
    if (tid < 128)
        atomicMin(&keys[m0 + tid], fmap(fminf(red[tid][0], red[tid][1])));
    // flush candidate buffer: one global atomic per block + coalesced copy
    unsigned int nl = lcnt; if (nl > LCAP) nl = LCAP;
    if (tid == 0) gbase_s = atomicAdd(cnt, nl);
    __syncthreads();
    unsigned int gb = gbase_s;
    for (unsigned int i = tid; i < nl; i += 256) {
        unsigned int gi = gb + i;
        if (gi < CAND_CAP2) cand[gi] = lbuf[i];
    }
}

// ---------------------------------------------------------------------------
// filter: keep raw candidates whose stored score <= global approx min + MARGIN
// (exactly the old pass2 set); compact into cand2 as (s<<32)|k.
__global__ __launch_bounds__(256) void filter_kernel(
    const u64* __restrict__ cand, unsigned int* __restrict__ cnt,
    const unsigned int* __restrict__ keys, u64* __restrict__ cand2) {
    unsigned int n = cnt[0];
    if (n > CAND_CAP2) n = CAND_CAP2;
    for (unsigned int i = blockIdx.x * 256 + threadIdx.x; i < n;
         i += gridDim.x * 256) {
        u64 e = cand[i];
        unsigned int sk = (unsigned int)e;
        unsigned int s = sk >> 14;
        float sc = unfmap((unsigned int)(e >> 32));
        float thr = unfmap(keys[s]) + MARGIN;
        if (sc <= thr) {
            unsigned int idx = atomicAdd(&cnt[1], 1u);
            if (idx < CAND_CAP)
                cand2[idx] = ((u64)s << 32) | (u64)(sk & 16383u);
        }
    }
}

// ---------------------------------------------------------------------------
// BMU refine: exact f32 dist^2 per candidate, one wave per candidate.
__global__ __launch_bounds__(256) void bmu_refine_kernel(
    const float* __restrict__ x, const float* __restrict__ w,
    const u64* __restrict__ cand2, const unsigned int* __restrict__ cnt,
    u64* __restrict__ keys2) {
    int lane = threadIdx.x & 63;
    int wid = blockIdx.x * 4 + (threadIdx.x >> 6);
    unsigned int n = cnt[1];
    if (n > CAND_CAP) n = CAND_CAP;
    for (unsigned int c = wid; c < n; c += 256 * 4) {
        u64 e = cand2[c];
        unsigned int s = (unsigned int)(e >> 32);
        unsigned int k = (unsigned int)e;
        float4 xv = *(const float4*)&x[(size_t)s * DIM + lane * 4];
        float4 wv = *(const float4*)&w[(size_t)k * DIM + lane * 4];
        float dx = xv.x - wv.x, dy = xv.y - wv.y;
        float dz = xv.z - wv.z, dw = xv.w - wv.w;
        float d = dx * dx + dy * dy + dz * dz + dw * dw;
        #pragma unroll
        for (int off = 32; off; off >>= 1) d += __shfl_down(d, off, 64);
        if (lane == 0)
            atomicMin(&keys2[s], ((u64)fmap(d) << 32) | k);
    }
}

// ---------------------------------------------------------------------------
// scatter: S[bmu(s)][:] += x[s][:], cntf[bmu(s)] += 1.  One wave per sample.
__global__ __launch_bounds__(256) void scatter_kernel(
    const float* __restrict__ x, const u64* __restrict__ keys2,
    float* __restrict__ S, float* __restrict__ cntf) {
    int lane = threadIdx.x & 63;
    int s = blockIdx.x * 4 + (threadIdx.x >> 6);
    unsigned int k = (unsigned int)keys2[s];
    float4 xv = *(const float4*)&x[(size_t)s * DIM + lane * 4];
    float* Sp = &S[(size_t)k * DIM + lane * 4];
    atomicAdd(Sp + 0, xv.x);
    atomicAdd(Sp + 1, xv.y);
    atomicAdd(Sp + 2, xv.z);
    atomicAdd(Sp + 3, xv.w);
    if (lane == 0) atomicAdd(&cntf[k], 1.0f);
}

// ---------------------------------------------------------------------------
// gemm1: T[i][m] = sum_a G[i][a] * S[a][m], m in [0,32768), f32.
__global__ __launch_bounds__(256) void gemm1_kernel(
    const float* __restrict__ G, const float* __restrict__ S, float* __restrict__ T) {
    __shared__ float Sl[128 * 68];
    int n0 = blockIdx.x * 64;
    int tid = threadIdx.x;
    #pragma unroll
    for (int q = 0; q < 8; ++q) {
        int idx = q * 256 + tid;
        int row = idx >> 4, c4 = (idx & 15) * 4;
        *(float4*)&Sl[row * 68 + c4] = *(const float4*)&S[(size_t)row * 32768 + n0 + c4];
    }
    __syncthreads();
    int ng = tid & 15, ig = tid >> 4;
    for (int pass = 0; pass < 2; ++pass) {
        int ibase = pass * 64 + ig * 4;
        float acc[4][4] = {};
        for (int a = 0; a < 128; ++a) {
            float4 sv = *(const float4*)&Sl[a * 68 + ng * 4];
            #pragma unroll
            for (int ii = 0; ii < 4; ++ii) {
                float g = G[(ibase + ii) * 128 + a];
                acc[ii][0] = fmaf(g, sv.x, acc[ii][0]);
                acc[ii][1] = fmaf(g, sv.y, acc[ii][1]);
                acc[ii][2] = fmaf(g, sv.z, acc[ii][2]);
                acc[ii][3] = fmaf(g, sv.w, acc[ii][3]);
            }
        }
        #pragma unroll
        for (int ii = 0; ii < 4; ++ii)
            *(float4*)&T[(size_t)(ibase + ii) * 32768 + n0 + ng * 4] =
                *(float4*)&acc[ii][0];
    }
}

// ---------------------------------------------------------------------------
// denom stage 1: M1[a][j] = sum_b2 cntf[a][b2] * G[b2][j]
__global__ void denom_s1_kernel(const float* __restrict__ cntf, const float* __restrict__ G,
                                float* __restrict__ M1) {
    int a = blockIdx.x, j = threadIdx.x;
    float acc = 0.f;
    for (int b2 = 0; b2 < 128; ++b2)
        acc = fmaf(cntf[a * 128 + b2], G[b2 * 128 + j], acc);
    M1[a * 128 + j] = acc;
}

// denom stage 2: denom[i][j] = sum_a G[i][a] * M1[a][j]
__global__ void denom_s2_kernel(const float* __restrict__ G, const float* __restrict__ M1,
                                float* __restrict__ denom) {
    int i = blockIdx.x, j = threadIdx.x;
    float acc = 0.f;
    for (int a = 0; a < 128; ++a)
        acc = fmaf(G[i * 128 + a], M1[a * 128 + j], acc);
    denom[i * 128 + j] = acc;
}

// ---------------------------------------------------------------------------
// gemm2 + finalize: out[i][j][d] = (sum_b2 G[j][b2] T[i][b2*256+d]) / denom[i][j]
__global__ __launch_bounds__(256) void gemm2_fin_kernel(
    const float* __restrict__ G, const float* __restrict__ T,
    const float* __restrict__ denom, const float* __restrict__ w,
    float* __restrict__ out) {
    __shared__ float Tl[128 * 68];
    int i = blockIdx.x, dq = blockIdx.y;
    int tid = threadIdx.x;
    #pragma unroll
    for (int q = 0; q < 8; ++q) {
        int idx = q * 256 + tid;
        int row = idx >> 4, c4 = (idx & 15) * 4;
        *(float4*)&Tl[row * 68 + c4] =
            *(const float4*)&T[(size_t)i * 32768 + row * 256 + dq * 64 + c4];
    }
    __syncthreads();
    int dg = tid & 15, jg = tid >> 4;
    for (int pass = 0; pass < 2; ++pass) {
        int jbase = pass * 64 + jg * 4;
        float acc[4][4] = {};
        for (int b2 = 0; b2 < 128; ++b2) {
            float4 tv = *(const float4*)&Tl[b2 * 68 + dg * 4];
            #pragma unroll
            for (int jj = 0; jj < 4; ++jj) {
                float g = G[(jbase + jj) * 128 + b2];
                acc[jj][0] = fmaf(g, tv.x, acc[jj][0]);
                acc[jj][1] = fmaf(g, tv.y, acc[jj][1]);
                acc[jj][2] = fmaf(g, tv.z, acc[jj][2]);
                acc[jj][3] = fmaf(g, tv.w, acc[jj][3]);
            }
        }
        #pragma unroll
        for (int jj = 0; jj < 4; ++jj) {
            int j = jbase + jj;
            float dv = denom[i * 128 + j];
            size_t e = (size_t)(i * 128 + j) * DIM + dq * 64 + dg * 4;
            float4 r;
            if (dv != 0.0f) {
                float inv = 1.0f / dv;
                r.x = acc[jj][0] * inv; r.y = acc[jj][1] * inv;
                r.z = acc[jj][2] * inv; r.w = acc[jj][3] * inv;
            } else {
                r = *(const float4*)&w[e];
            }
            *(float4*)&out[e] = r;
        }
    }
}

// ---------------------------------------------------------------------------
extern "C" void kernel_launch(void* const* d_in, const int* in_sizes, int n_in,
                              void* d_out, int out_size, void* d_ws, size_t ws_size,
                              hipStream_t stream) {
    const float* data = (const float*)d_in[0];   // [8192, 256] f32
    const float* w    = (const float*)d_in[1];   // [128,128,256] f32
    const int*   itp  = (const int*)d_in[2];     // scalar
    float* out = (float*)d_out;                  // [128,128,256] f32

    char* ws = (char*)d_ws;
    size_t off = 0;
    float*        wsq   = (float*)(ws + off);        off += 65536;     //  64 KB
    unsigned int* keys  = (unsigned int*)(ws + off); off += 65536;     //  64 KB (u32 fmap scores)
    u64*          keys2 = (u64*)(ws + off);          off += 65536;     //  64 KB (exact dist|k)
    unsigned int* cnt   = (unsigned int*)(ws + off); off += 65536;     //  64 KB (cnt[0]=raw, cnt[1]=survivors)
    float*        G     = (float*)(ws + off);        off += 65536;     //  64 KB [128][128]
    float*        cntf  = (float*)(ws + off);        off += 65536;     //  64 KB [a][b2]
    float*        M1    = (float*)(ws + off);        off += 65536;     //  64 KB
    float*        denom = (float*)(ws + off);        off += 65536;     //  64 KB
    ushort*       xf    = (ushort*)(ws + off);       off += 4194304;   //   4 MB fp16 swizzled
    ushort*       wf    = (ushort*)(ws + off);       off += 8388608;   //   8 MB fp16 swizzled
    u64*          cand2 = (u64*)(ws + off);          off += 1048576;   //   1 MB survivors
    float*        S     = (float*)(ws + off);        off += 16777216;  //  16 MB [c][d]
    float*        T     = (float*)(ws + off);        off += 16777216;  //  16 MB [i][32768]
    // raw candidate list aliases T: T is dead until gemm1, cand dead after filter
    u64*          cand  = (u64*)T;                   // 2M entries = 16 MB

    setup_all_kernel<<<4096, 256, 0, stream>>>(S, G, cntf, keys, keys2, cnt, itp);
    cvt_all_kernel<<<(BS + KTOT) / 4, 256, 0, stream>>>(data, w, xf, wf, wsq);
    bmu_fused_kernel<<<dim3(64, 16), 256, 0, stream>>>(xf, wf, wsq, keys, cand, cnt);
    filter_kernel<<<1024, 256, 0, stream>>>(cand, cnt, keys, cand2);
    bmu_refine_kernel<<<256, 256, 0, stream>>>(data, w, cand2, cnt, keys2);
    scatter_kernel<<<BS / 4, 256, 0, stream>>>(data, keys2, S, cntf);
    gemm1_kernel<<<512, 256, 0, stream>>>(G, S, T);
    denom_s1_kernel<<<128, 128, 0, stream>>>(cntf, G, M1);
    denom_s2_kernel<<<128, 128, 0, stream>>>(G, M1, denom);
    gemm2_fin_kernel<<<dim3(128, 4), 256, 0, stream>>>(G, T, denom, w, out);
}

// Round 2
// 388.067 us; speedup vs baseline: 1.1013x; 1.1013x over previous
//
#include <hip/hip_runtime.h>
#include <hip/hip_fp16.h>

// Problem constants
#define BS    8192
#define DIM   256
#define KTOT  16384      // 128x128 codebook
#define CAND_CAP2 2097152    // raw emission list (aliases T, 16 MB)
#define LCAP 1024            // per-block LDS emission buffer entries
#define MARGIN 1.0f

typedef __attribute__((ext_vector_type(8))) _Float16 half8;
typedef __attribute__((ext_vector_type(4))) float f32x4;
typedef unsigned long long u64;

__device__ inline ushort f2h(float f) { return __half_as_ushort(__float2half(f)); }

// async global->LDS, 16B per lane; lds dest = wave-uniform base + lane*16
__device__ inline void gload_lds16(const void* g, void* l) {
    __builtin_amdgcn_global_load_lds(
        (const __attribute__((address_space(1))) unsigned int*)g,
        (__attribute__((address_space(3))) unsigned int*)l, 16, 0, 0);
}

// order-preserving f32 -> u32 map (ascending) and inverse
__device__ inline unsigned int fmap(float f) {
    unsigned int b = __float_as_uint(f);
    return (b & 0x80000000u) ? ~b : (b | 0x80000000u);
}
__device__ inline float unfmap(unsigned int m) {
    return (m & 0x80000000u) ? __uint_as_float(m & 0x7FFFFFFFu)
                             : __uint_as_float(~m);
}

// ---------------------------------------------------------------------------
// setup: zero S (16 MB), G table, zero cntf, init keys(u32)/keys2(u64), cnt.
__global__ void setup_all_kernel(float* __restrict__ S, float* __restrict__ G,
                                 float* __restrict__ cntf, unsigned int* __restrict__ keys,
                                 u64* __restrict__ keys2, unsigned int* __restrict__ cnt,
                                 const int* __restrict__ itp) {
    int idx = blockIdx.x * 256 + threadIdx.x;
    *(float4*)&S[(size_t)idx * 4] = make_float4(0.f, 0.f, 0.f, 0.f);
    if (idx < KTOT) {
        float itf = (float)itp[0];
        const float START_SIGMA = 64.0f;
        const float TAU = (float)(20.0 / 4.1588830833596715);  // 20 / ln(64)
        float sigma = START_SIGMA * expf(-itf / TAU);
        float d2 = 2.0f * sigma * sigma;
        int i = idx >> 7, j = idx & 127;
        float diff = (float)(i - j);
        G[idx] = expf(-(diff * diff) / d2);
        cntf[idx] = 0.f;
    }
    if (idx < BS) { keys[idx] = 0xFFFFFFFFu; keys2[idx] = ~0ULL; }
    if (idx == 0) cnt[0] = 0u;
}

// ---------------------------------------------------------------------------
// x,w -> fp16 with XOR-swizzled 32-half windows (block c -> c ^ ((row>>1)&3)),
// + wsq for w rows.  One wave per row; rows [0,BS) are x, [BS, BS+KTOT) are w.
__global__ void cvt_all_kernel(const float* __restrict__ x, const float* __restrict__ w,
                               ushort* __restrict__ xf, ushort* __restrict__ wf,
                               float* __restrict__ wsq) {
    int wid = threadIdx.x >> 6, lane = threadIdx.x & 63;
    int row = blockIdx.x * 4 + wid;
    int h = lane * 4;                      // half index 0..255
    int window = h >> 5, c = (h >> 3) & 3, off = h & 7;
    if (row < BS) {
        int swpos = (window << 5) + (((c ^ ((row >> 1) & 3)) << 3)) + off;
        float4 v = *(const float4*)&x[(size_t)row * DIM + h];
        ushort4 hv;
        hv.x = f2h(v.x); hv.y = f2h(v.y); hv.z = f2h(v.z); hv.w = f2h(v.w);
        *(ushort4*)&xf[(size_t)row * DIM + swpos] = hv;
    } else {
        int r = row - BS;
        int swpos = (window << 5) + (((c ^ ((r >> 1) & 3)) << 3)) + off;
        float4 v = *(const float4*)&w[(size_t)r * DIM + h];
        ushort4 hv;
        hv.x = f2h(v.x); hv.y = f2h(v.y); hv.z = f2h(v.z); hv.w = f2h(v.w);
        *(ushort4*)&wf[(size_t)r * DIM + swpos] = hv;
        float s = v.x * v.x + v.y * v.y + v.z * v.z + v.w * v.w;
        #pragma unroll
        for (int o = 32; o; o >>= 1) s += __shfl_down(s, o, 64);
        if (lane == 0) wsq[r] = s;
    }
}

// ---------------------------------------------------------------------------
// Seed pass: min over 2048 codebook rows (one 128-row k-tile per block at
// kbase = blockIdx.y*1024).  Same GEMM structure as the main pass, 1/8 work.
// keys[s] = atomicMin of fmap(seed min) -> tight emission threshold.
__global__ __launch_bounds__(256, 4) void bmu_seed_kernel(
    const ushort* __restrict__ xf, const ushort* __restrict__ wf,
    const float* __restrict__ wsq, unsigned int* __restrict__ keys) {
    __shared__ ushort A[128 * 32];   //  8 KB
    __shared__ ushort B[128 * 32];   //  8 KB
    __shared__ float red[128][2];

    int m0 = blockIdx.x * 128;
    int k0 = blockIdx.y * 1024;      // one kt tile: rows k0..k0+127
    int tid = threadIdx.x, w = tid >> 6, lane = tid & 63;
    int wm = (w & 1) * 64, wn = (w >> 1) * 64;
    int lm = lane & 15, quad = lane >> 4;
    int sw = (quad ^ ((lm >> 1) & 3)) * 8;
    int srow = lane >> 2, scol = (lane & 3) * 8;

    f32x4 acc[4][4];
    #pragma unroll
    for (int mi = 0; mi < 4; ++mi)
        #pragma unroll
        for (int ni = 0; ni < 4; ++ni)
            acc[mi][ni] = (f32x4){0.f, 0.f, 0.f, 0.f};

    for (int kb = 0; kb < DIM; kb += 32) {
        size_t axoff = (size_t)(m0 + w * 32 + srow) * DIM + kb + scol;
        size_t bxoff = (size_t)(k0 + w * 32 + srow) * DIM + kb + scol;
        gload_lds16(xf + axoff,            &A[(w * 32) * 32]);
        gload_lds16(xf + axoff + 16 * DIM, &A[(w * 32 + 16) * 32]);
        gload_lds16(wf + bxoff,            &B[(w * 32) * 32]);
        gload_lds16(wf + bxoff + 16 * DIM, &B[(w * 32 + 16) * 32]);
        __syncthreads();
        half8 av[4], bv[4];
        #pragma unroll
        for (int mi = 0; mi < 4; ++mi)
            av[mi] = *(const half8*)&A[(wm + mi * 16 + lm) * 32 + sw];
        #pragma unroll
        for (int ni = 0; ni < 4; ++ni)
            bv[ni] = *(const half8*)&B[(wn + ni * 16 + lm) * 32 + sw];
        #pragma unroll
        for (int mi = 0; mi < 4; ++mi)
            #pragma unroll
            for (int ni = 0; ni < 4; ++ni)
                acc[mi][ni] = __builtin_amdgcn_mfma_f32_16x16x32_f16(
                    av[mi], bv[ni], acc[mi][ni], 0, 0, 0);
        __syncthreads();
    }
    float wsqv[4];
    #pragma unroll
    for (int ni = 0; ni < 4; ++ni) wsqv[ni] = wsq[k0 + wn + ni * 16 + lm];
    #pragma unroll
    for (int mi = 0; mi < 4; ++mi)
        #pragma unroll
        for (int r = 0; r < 4; ++r) {
            float b = 3.4e38f;
            #pragma unroll
            for (int ni = 0; ni < 4; ++ni)
                b = fminf(b, fmaf(-2.0f, acc[mi][ni][r], wsqv[ni]));
            #pragma unroll
            for (int mask = 1; mask < 16; mask <<= 1)
                b = fminf(b, __shfl_xor(b, mask, 64));
            if (lm == 0) red[wm + mi * 16 + quad * 4 + r][w >> 1] = b;
        }
    __syncthreads();
    if (tid < 128)
        atomicMin(&keys[m0 + tid], fmap(fminf(red[tid][0], red[tid][1])));
}

// ---------------------------------------------------------------------------
// Main fused pass: single full fp16 GEMM.  Constant emission threshold
// thr = seed(keys) + MARGIN (seed >= global min => emitted set is a superset
// of {sc <= globalmin + MARGIN}).  Per-lane running min -> final keys.
// Emissions staged in an 8 KB LDS buffer, one flush per block.
__global__ __launch_bounds__(256, 4) void bmu_fused_kernel(
    const ushort* __restrict__ xf, const ushort* __restrict__ wf,
    const float* __restrict__ wsq, unsigned int* __restrict__ keys,
    u64* __restrict__ cand, unsigned int* __restrict__ cnt) {
    __shared__ ushort A[128 * 32];   //  8 KB
    __shared__ ushort B[128 * 32];   //  8 KB
    __shared__ float red[128][2];
    __shared__ u64 lbuf[LCAP];       //  8 KB candidate staging
    __shared__ unsigned int lcnt, gbase_s;

    int m0 = blockIdx.x * 128;
    int kbase = blockIdx.y * 1024;
    int tid = threadIdx.x, w = tid >> 6, lane = tid & 63;
    int wm = (w & 1) * 64, wn = (w >> 1) * 64;
    int lm = lane & 15, quad = lane >> 4;
    int sw = (quad ^ ((lm >> 1) & 3)) * 8;
    int srow = lane >> 2, scol = (lane & 3) * 8;

    if (tid == 0) lcnt = 0u;

    // constant per-row emission threshold from the seed pass
    float thr[4][4];
    float wbest[4][4];
    #pragma unroll
    for (int mi = 0; mi < 4; ++mi)
        #pragma unroll
        for (int r = 0; r < 4; ++r) {
            thr[mi][r] = unfmap(keys[m0 + wm + mi * 16 + quad * 4 + r]) + MARGIN;
            wbest[mi][r] = 3.4e38f;
        }

    for (int kt = 0; kt < 8; ++kt) {
        int k0 = kbase + kt * 128;
        f32x4 acc[4][4];
        #pragma unroll
        for (int mi = 0; mi < 4; ++mi)
            #pragma unroll
            for (int ni = 0; ni < 4; ++ni)
                acc[mi][ni] = (f32x4){0.f, 0.f, 0.f, 0.f};

        for (int kb = 0; kb < DIM; kb += 32) {
            size_t axoff = (size_t)(m0 + w * 32 + srow) * DIM + kb + scol;
            size_t bxoff = (size_t)(k0 + w * 32 + srow) * DIM + kb + scol;
            gload_lds16(xf + axoff,            &A[(w * 32) * 32]);
            gload_lds16(xf + axoff + 16 * DIM, &A[(w * 32 + 16) * 32]);
            gload_lds16(wf + bxoff,            &B[(w * 32) * 32]);
            gload_lds16(wf + bxoff + 16 * DIM, &B[(w * 32 + 16) * 32]);
            __syncthreads();
            half8 av[4], bv[4];
            #pragma unroll
            for (int mi = 0; mi < 4; ++mi)
                av[mi] = *(const half8*)&A[(wm + mi * 16 + lm) * 32 + sw];
            #pragma unroll
            for (int ni = 0; ni < 4; ++ni)
                bv[ni] = *(const half8*)&B[(wn + ni * 16 + lm) * 32 + sw];
            #pragma unroll
            for (int mi = 0; mi < 4; ++mi)
                #pragma unroll
                for (int ni = 0; ni < 4; ++ni)
                    acc[mi][ni] = __builtin_amdgcn_mfma_f32_16x16x32_f16(
                        av[mi], bv[ni], acc[mi][ni], 0, 0, 0);
            __syncthreads();
        }
        // fold + emit for this k-tile (no cross-lane reduce in the hot loop)
        float wsqv[4];
        #pragma unroll
        for (int ni = 0; ni < 4; ++ni) wsqv[ni] = wsq[k0 + wn + ni * 16 + lm];
        #pragma unroll
        for (int mi = 0; mi < 4; ++mi)
            #pragma unroll
            for (int r = 0; r < 4; ++r) {
                unsigned int sp =
                    (unsigned int)(m0 + wm + mi * 16 + quad * 4 + r) << 14;
                #pragma unroll
                for (int ni = 0; ni < 4; ++ni) {
                    float sc = fmaf(-2.0f, acc[mi][ni][r], wsqv[ni]);
                    wbest[mi][r] = fminf(wbest[mi][r], sc);
                    if (sc <= thr[mi][r]) {
                        u64 v = ((u64)fmap(sc) << 32) |
                                (u64)(sp | (unsigned int)(k0 + wn + ni * 16 + lm));
                        unsigned int idx = atomicAdd(&lcnt, 1u);
                        if (idx < LCAP) lbuf[idx] = v;
                        else {                      // truly-rare overflow fallback
                            unsigned int gi = atomicAdd(cnt, 1u);
                            if (gi < CAND_CAP2) cand[gi] = v;
                        }
                    }
                }
            }
    }
    // epilogue: per-sample min -> keys
    #pragma unroll
    for (int mi = 0; mi < 4; ++mi)
        #pragma unroll
        for (int r = 0; r < 4; ++r) {
            float b = wbest[mi][r];
            #pragma unroll
            for (int mask = 1; mask < 16; mask <<= 1)
                b = fminf(b, __shfl_xor(b, mask, 64));
            if (lm == 0) red[wm + mi * 16 + quad * 4 + r][w >> 1] = b;
        }
    __syncthreads();
    if (tid < 128)
        atomicMin(&keys[m0 + tid], fmap(fminf(red[tid][0], red[tid][1])));
    // flush candidate buffer: one global atomic per block + coalesced copy
    unsigned int nl = lcnt; if (nl > LCAP) nl = LCAP;
    if (tid == 0) gbase_s = atomicAdd(cnt, nl);
    __syncthreads();
    unsigned int gb = gbase_s;
    for (unsigned int i = tid; i < nl; i += 256) {
        unsigned int gi = gb + i;
        if (gi < CAND_CAP2) cand[gi] = lbuf[i];
    }
}

// ---------------------------------------------------------------------------
// BMU refine (with inline filter): for each raw candidate, wave-uniform check
// of stored fp16 score vs final approx min + MARGIN; survivors get exact f32
// dist^2; one wave per candidate.
__global__ __launch_bounds__(256) void bmu_refine_kernel(
    const float* __restrict__ x, const float* __restrict__ w,
    const u64* __restrict__ cand, const unsigned int* __restrict__ cnt,
    const unsigned int* __restrict__ keys, u64* __restrict__ keys2) {
    int lane = threadIdx.x & 63;
    int wid = blockIdx.x * 4 + (threadIdx.x >> 6);
    unsigned int n = cnt[0];
    if (n > CAND_CAP2) n = CAND_CAP2;
    for (unsigned int c = wid; c < n; c += gridDim.x * 4) {
        u64 e = cand[c];
        unsigned int sk = (unsigned int)e;
        unsigned int s = sk >> 14;
        unsigned int k = sk & 16383u;
        float sc = unfmap((unsigned int)(e >> 32));
        if (sc > unfmap(keys[s]) + MARGIN) continue;   // wave-uniform skip
        float4 xv = *(const float4*)&x[(size_t)s * DIM + lane * 4];
        float4 wv = *(const float4*)&w[(size_t)k * DIM + lane * 4];
        float dx = xv.x - wv.x, dy = xv.y - wv.y;
        float dz = xv.z - wv.z, dw = xv.w - wv.w;
        float d = dx * dx + dy * dy + dz * dz + dw * dw;
        #pragma unroll
        for (int off = 32; off; off >>= 1) d += __shfl_down(d, off, 64);
        if (lane == 0)
            atomicMin(&keys2[s], ((u64)fmap(d) << 32) | k);
    }
}

// ---------------------------------------------------------------------------
// scatter: S[bmu(s)][:] += x[s][:], cntf[bmu(s)] += 1.  One wave per sample.
__global__ __launch_bounds__(256) void scatter_kernel(
    const float* __restrict__ x, const u64* __restrict__ keys2,
    float* __restrict__ S, float* __restrict__ cntf) {
    int lane = threadIdx.x & 63;
    int s = blockIdx.x * 4 + (threadIdx.x >> 6);
    unsigned int k = (unsigned int)keys2[s];
    float4 xv = *(const float4*)&x[(size_t)s * DIM + lane * 4];
    float* Sp = &S[(size_t)k * DIM + lane * 4];
    atomicAdd(Sp + 0, xv.x);
    atomicAdd(Sp + 1, xv.y);
    atomicAdd(Sp + 2, xv.z);
    atomicAdd(Sp + 3, xv.w);
    if (lane == 0) atomicAdd(&cntf[k], 1.0f);
}

// ---------------------------------------------------------------------------
// gemm1: T[i][m] = sum_a G[i][a] * S[a][m], m in [0,32768), f32.
__global__ __launch_bounds__(256) void gemm1_kernel(
    const float* __restrict__ G, const float* __restrict__ S, float* __restrict__ T) {
    __shared__ float Sl[128 * 68];
    int n0 = blockIdx.x * 64;
    int tid = threadIdx.x;
    #pragma unroll
    for (int q = 0; q < 8; ++q) {
        int idx = q * 256 + tid;
        int row = idx >> 4, c4 = (idx & 15) * 4;
        *(float4*)&Sl[row * 68 + c4] = *(const float4*)&S[(size_t)row * 32768 + n0 + c4];
    }
    __syncthreads();
    int ng = tid & 15, ig = tid >> 4;
    for (int pass = 0; pass < 2; ++pass) {
        int ibase = pass * 64 + ig * 4;
        float acc[4][4] = {};
        for (int a = 0; a < 128; ++a) {
            float4 sv = *(const float4*)&Sl[a * 68 + ng * 4];
            #pragma unroll
            for (int ii = 0; ii < 4; ++ii) {
                float g = G[(ibase + ii) * 128 + a];
                acc[ii][0] = fmaf(g, sv.x, acc[ii][0]);
                acc[ii][1] = fmaf(g, sv.y, acc[ii][1]);
                acc[ii][2] = fmaf(g, sv.z, acc[ii][2]);
                acc[ii][3] = fmaf(g, sv.w, acc[ii][3]);
            }
        }
        #pragma unroll
        for (int ii = 0; ii < 4; ++ii)
            *(float4*)&T[(size_t)(ibase + ii) * 32768 + n0 + ng * 4] =
                *(float4*)&acc[ii][0];
    }
}

// ---------------------------------------------------------------------------
// denom stage 1: M1[a][j] = sum_b2 cntf[a][b2] * G[b2][j]
__global__ void denom_s1_kernel(const float* __restrict__ cntf, const float* __restrict__ G,
                                float* __restrict__ M1) {
    int a = blockIdx.x, j = threadIdx.x;
    float acc = 0.f;
    for (int b2 = 0; b2 < 128; ++b2)
        acc = fmaf(cntf[a * 128 + b2], G[b2 * 128 + j], acc);
    M1[a * 128 + j] = acc;
}

// denom stage 2: denom[i][j] = sum_a G[i][a] * M1[a][j]
__global__ void denom_s2_kernel(const float* __restrict__ G, const float* __restrict__ M1,
                                float* __restrict__ denom) {
    int i = blockIdx.x, j = threadIdx.x;
    float acc = 0.f;
    for (int a = 0; a < 128; ++a)
        acc = fmaf(G[i * 128 + a], M1[a * 128 + j], acc);
    denom[i * 128 + j] = acc;
}

// ---------------------------------------------------------------------------
// gemm2 + finalize: out[i][j][d] = (sum_b2 G[j][b2] T[i][b2*256+d]) / denom[i][j]
__global__ __launch_bounds__(256) void gemm2_fin_kernel(
    const float* __restrict__ G, const float* __restrict__ T,
    const float* __restrict__ denom, const float* __restrict__ w,
    float* __restrict__ out) {
    __shared__ float Tl[128 * 68];
    int i = blockIdx.x, dq = blockIdx.y;
    int tid = threadIdx.x;
    #pragma unroll
    for (int q = 0; q < 8; ++q) {
        int idx = q * 256 + tid;
        int row = idx >> 4, c4 = (idx & 15) * 4;
        *(float4*)&Tl[row * 68 + c4] =
            *(const float4*)&T[(size_t)i * 32768 + row * 256 + dq * 64 + c4];
    }
    __syncthreads();
    int dg = tid & 15, jg = tid >> 4;
    for (int pass = 0; pass < 2; ++pass) {
        int jbase = pass * 64 + jg * 4;
        float acc[4][4] = {};
        for (int b2 = 0; b2 < 128; ++b2) {
            float4 tv = *(const float4*)&Tl[b2 * 68 + dg * 4];
            #pragma unroll
            for (int jj = 0; jj < 4; ++jj) {
                float g = G[(jbase + jj) * 128 + b2];
                acc[jj][0] = fmaf(g, tv.x, acc[jj][0]);
                acc[jj][1] = fmaf(g, tv.y, acc[jj][1]);
                acc[jj][2] = fmaf(g, tv.z, acc[jj][2]);
                acc[jj][3] = fmaf(g, tv.w, acc[jj][3]);
            }
        }
        #pragma unroll
        for (int jj = 0; jj < 4; ++jj) {
            int j = jbase + jj;
            float dv = denom[i * 128 + j];
            size_t e = (size_t)(i * 128 + j) * DIM + dq * 64 + dg * 4;
            float4 r;
            if (dv != 0.0f) {
                float inv = 1.0f / dv;
                r.x = acc[jj][0] * inv; r.y = acc[jj][1] * inv;
                r.z = acc[jj][2] * inv; r.w = acc[jj][3] * inv;
            } else {
                r = *(const float4*)&w[e];
            }
            *(float4*)&out[e] = r;
        }
    }
}

// ---------------------------------------------------------------------------
extern "C" void kernel_launch(void* const* d_in, const int* in_sizes, int n_in,
                              void* d_out, int out_size, void* d_ws, size_t ws_size,
                              hipStream_t stream) {
    const float* data = (const float*)d_in[0];   // [8192, 256] f32
    const float* w    = (const float*)d_in[1];   // [128,128,256] f32
    const int*   itp  = (const int*)d_in[2];     // scalar
    float* out = (float*)d_out;                  // [128,128,256] f32

    char* ws = (char*)d_ws;
    size_t off = 0;
    float*        wsq   = (float*)(ws + off);        off += 65536;     //  64 KB
    unsigned int* keys  = (unsigned int*)(ws + off); off += 65536;     //  64 KB (u32 fmap scores)
    u64*          keys2 = (u64*)(ws + off);          off += 65536;     //  64 KB (exact dist|k)
    unsigned int* cnt   = (unsigned int*)(ws + off); off += 65536;     //  64 KB
    float*        G     = (float*)(ws + off);        off += 65536;     //  64 KB [128][128]
    float*        cntf  = (float*)(ws + off);        off += 65536;     //  64 KB [a][b2]
    float*        M1    = (float*)(ws + off);        off += 65536;     //  64 KB
    float*        denom = (float*)(ws + off);        off += 65536;     //  64 KB
    ushort*       xf    = (ushort*)(ws + off);       off += 4194304;   //   4 MB fp16 swizzled
    ushort*       wf    = (ushort*)(ws + off);       off += 8388608;   //   8 MB fp16 swizzled
    u64*          spare = (u64*)(ws + off);          off += 1048576;   //   1 MB (unused)
    float*        S     = (float*)(ws + off);        off += 16777216;  //  16 MB [c][d]
    float*        T     = (float*)(ws + off);        off += 16777216;  //  16 MB [i][32768]
    // raw candidate list aliases T: T is dead until gemm1, cand dead after refine
    u64*          cand  = (u64*)T;                   // 2M entries = 16 MB
    (void)spare;

    setup_all_kernel<<<4096, 256, 0, stream>>>(S, G, cntf, keys, keys2, cnt, itp);
    cvt_all_kernel<<<(BS + KTOT) / 4, 256, 0, stream>>>(data, w, xf, wf, wsq);
    bmu_seed_kernel<<<dim3(64, 16), 256, 0, stream>>>(xf, wf, wsq, keys);
    bmu_fused_kernel<<<dim3(64, 16), 256, 0, stream>>>(xf, wf, wsq, keys, cand, cnt);
    bmu_refine_kernel<<<512, 256, 0, stream>>>(data, w, cand, cnt, keys, keys2);
    scatter_kernel<<<BS / 4, 256, 0, stream>>>(data, keys2, S, cntf);
    gemm1_kernel<<<512, 256, 0, stream>>>(G, S, T);
    denom_s1_kernel<<<128, 128, 0, stream>>>(cntf, G, M1);
    denom_s2_kernel<<<128, 128, 0, stream>>>(G, M1, denom);
    gemm2_fin_kernel<<<dim3(128, 4), 256, 0, stream>>>(G, T, denom, w, out);
}